// Round 23
// baseline (121.434 us; speedup 1.0000x reference)
//
#include <hip/hip_runtime.h>

#define DEV __device__ __forceinline__

typedef __bf16 bf16x8 __attribute__((ext_vector_type(8)));
typedef float f32x4 __attribute__((ext_vector_type(4)));
typedef float f32x16 __attribute__((ext_vector_type(16)));
typedef unsigned u32x4 __attribute__((ext_vector_type(4)));

constexpr int S_LEN = 2048;
constexpr int DMODEL = 1024;
constexpr int NHEAD = 16;
constexpr int HDIM = 64;
constexpr int BATCH = 2;
constexpr int MROWS = BATCH * S_LEN;  // 4096
constexpr float QSCALE = 0.125f * 1.44269504088896f;  // 1/sqrt(64) * log2(e)

DEV short f2bf(float x) {
  unsigned u = __builtin_bit_cast(unsigned, x);
  unsigned r = u + 0x7fffu + ((u >> 16) & 1u);
  return (short)(r >> 16);
}

#define MFMA16(a, b, c) __builtin_amdgcn_mfma_f32_16x16x32_bf16((a), (b), (c), 0, 0, 0)
#define MFMA32(a, b, c) __builtin_amdgcn_mfma_f32_32x32x16_bf16((a), (b), (c), 0, 0, 0)
#define GLL16(g, l)                                                                     \
  __builtin_amdgcn_global_load_lds((const __attribute__((address_space(1))) void*)(g),  \
                                   (__attribute__((address_space(3))) void*)(l), 16, 0, 0)

DEV unsigned cvt_pk_bf16(float a, float b) {
  unsigned r;
  asm("v_cvt_pk_bf16_f32 %0, %1, %2" : "=v"(r) : "v"(a), "v"(b));
  return r;
}
DEV void swap32(unsigned& a, unsigned& b) {
  asm("v_permlane32_swap_b32 %0, %1" : "+v"(a), "+v"(b));
}

// ---------------- fused fp32 -> bf16 convert: [x | Wq | Wk | Wv | Wo] ----------------
__global__ void cvt_all(const float* __restrict__ x, const float* __restrict__ wq,
                        const float* __restrict__ wk, const float* __restrict__ wv,
                        const float* __restrict__ wo, short* __restrict__ out) {
  const size_t XNe = (size_t)MROWS * DMODEL;   // 4M
  const size_t WNe = (size_t)DMODEL * DMODEL;  // 1M = 2^20
  const size_t tot = XNe + 4 * WNe;
  size_t i = ((size_t)blockIdx.x * blockDim.x + threadIdx.x) * 4;
  const size_t stride = (size_t)gridDim.x * blockDim.x * 4;
  for (; i < tot; i += stride) {
    const float* src;
    size_t off;
    if (i < XNe) {
      src = x;
      off = i;
    } else {
      const size_t k = i - XNe;
      const int seg = (int)(k >> 20);
      off = k & (WNe - 1);
      src = seg == 0 ? wq : seg == 1 ? wk : seg == 2 ? wv : wo;
    }
    float4 v = *(const float4*)&src[off];
    short4 r;
    r.x = f2bf(v.x);
    r.y = f2bf(v.y);
    r.z = f2bf(v.z);
    r.w = f2bf(v.w);
    *(short4*)&out[i] = r;
  }
}

// ------------- QKV GEMM, 8-phase 256x256 (T3+T4): BK=64, 8 waves, 128KB LDS ----------
// R23: STAGE issued BEFORE the ds_reads in each phase (earlier flight, same hazards).
__global__ __launch_bounds__(512) void gemm_qkv8(const short* __restrict__ A,
                                                 const short* __restrict__ Bt,
                                                 short* __restrict__ outb) {
  constexpr int K = DMODEL;
  constexpr int NT = K / 64;  // 16
  constexpr size_t XN = (size_t)MROWS * DMODEL;
  __shared__ short Alds[2][256 * 64];  // 64KB
  __shared__ short Blds[2][256 * 64];  // 64KB
  const int tid = threadIdx.x;
  const int w = tid >> 6, l = tid & 63;
  const int lr = l & 15, lh = l >> 4;  // lh 0..3
  const int wm = w >> 2, wn = w & 3;   // wave tile: rows wm*128, cols wn*64
  const int tm = blockIdx.x, tn = blockIdx.y;
  const bool vswap = (tn >= 8);

  const int l3 = l >> 3;                // 0..7
  const int scol = ((l & 7) ^ l3) * 8;  // pre-swizzled global col (row&7 == l3)

  f32x4 acc[8][4] = {};
  bf16x8 af[8], bfv[4];

#define STAGE_A(KT2, NB, H)                                                   \
  {                                                                           \
    _Pragma("unroll") for (int i = 0; i < 2; ++i) {                           \
      const int r = w * 8 + l3 + i * 128 + (H)*64;                            \
      GLL16(A + (size_t)(tm * 256 + r) * K + (KT2)*64 + scol,                 \
            &Alds[NB][(i * 1024 + (H)*512 + w * 64) * 8]);                    \
    }                                                                         \
  }
#define STAGE_B(KT2, NB, J)                                                   \
  {                                                                           \
    _Pragma("unroll") for (int i = 0; i < 2; ++i) {                           \
      const int g = i * 2 + (w >> 2);                                         \
      const int r = g * 64 + (J)*32 + (w & 3) * 8 + l3;                       \
      GLL16(Bt + (size_t)(tn * 256 + r) * K + (KT2)*64 + scol,                \
            &Blds[NB][(g * 512 + (J)*256 + (w & 3) * 64) * 8]);               \
    }                                                                         \
  }

#define RD_A(BUF, MH)                                                          \
  _Pragma("unroll") for (int mi = 0; mi < 4; ++mi) {                           \
    const int r = wm * 128 + (MH)*64 + mi * 16 + lr;                           \
    af[mi * 2 + 0] = *(const bf16x8*)&Alds[BUF][r * 64 + 8 * (lh ^ (r & 7))];  \
    af[mi * 2 + 1] =                                                           \
        *(const bf16x8*)&Alds[BUF][r * 64 + 8 * ((4 + lh) ^ (r & 7))];         \
  }
#define RD_B(BUF, NH)                                                          \
  _Pragma("unroll") for (int ni = 0; ni < 2; ++ni) {                           \
    const int r = wn * 64 + (NH)*32 + ni * 16 + lr;                            \
    bfv[ni * 2 + 0] = *(const bf16x8*)&Blds[BUF][r * 64 + 8 * (lh ^ (r & 7))]; \
    bfv[ni * 2 + 1] =                                                          \
        *(const bf16x8*)&Blds[BUF][r * 64 + 8 * ((4 + lh) ^ (r & 7))];         \
  }

#define MM(MH, NH)                                                              \
  {                                                                             \
    __builtin_amdgcn_s_setprio(1);                                              \
    if (!vswap) {                                                               \
      _Pragma("unroll") for (int ks = 0; ks < 2; ++ks)                          \
      _Pragma("unroll") for (int mi = 0; mi < 4; ++mi)                          \
      _Pragma("unroll") for (int ni = 0; ni < 2; ++ni)                          \
          acc[(MH)*4 + mi][(NH)*2 + ni] = MFMA16(                               \
              af[mi * 2 + ks], bfv[ni * 2 + ks], acc[(MH)*4 + mi][(NH)*2 + ni]);\
    } else {                                                                    \
      _Pragma("unroll") for (int ks = 0; ks < 2; ++ks)                          \
      _Pragma("unroll") for (int mi = 0; mi < 4; ++mi)                          \
      _Pragma("unroll") for (int ni = 0; ni < 2; ++ni)                          \
          acc[(MH)*4 + mi][(NH)*2 + ni] = MFMA16(                               \
              bfv[ni * 2 + ks], af[mi * 2 + ks], acc[(MH)*4 + mi][(NH)*2 + ni]);\
    }                                                                           \
    __builtin_amdgcn_s_setprio(0);                                              \
  }

#define BARR()                       \
  __builtin_amdgcn_s_barrier();      \
  asm volatile("" ::: "memory")
#define VW4() asm volatile("s_waitcnt vmcnt(4)" ::: "memory")

  STAGE_A(0, 0, 0);
  STAGE_B(0, 0, 0);
  STAGE_B(0, 0, 1);
  STAGE_A(0, 0, 1);

  for (int kt = 0; kt < NT - 1; ++kt) {
    const int buf = kt & 1, nb = buf ^ 1;
    // phase 0 (staging issued first — earlier flight; different buffer, no hazard)
    VW4();
    BARR();
    STAGE_A(kt + 1, nb, 0);
    RD_A(buf, 0);
    RD_B(buf, 0);
    MM(0, 0);
    // phase 1
    VW4();
    BARR();
    STAGE_B(kt + 1, nb, 0);
    RD_B(buf, 1);
    MM(0, 1);
    // phase 2
    VW4();
    BARR();
    STAGE_B(kt + 1, nb, 1);
    RD_A(buf, 1);
    RD_B(buf, 0);
    MM(1, 0);
    // phase 3
    BARR();
    STAGE_A(kt + 1, nb, 1);
    RD_B(buf, 1);
    MM(1, 1);
  }
  {  // peeled last tile
    const int buf = (NT - 1) & 1;
    VW4();
    BARR();
    RD_A(buf, 0);
    RD_B(buf, 0);
    MM(0, 0);
    asm volatile("s_waitcnt vmcnt(2)" ::: "memory");
    BARR();
    RD_B(buf, 1);
    MM(0, 1);
    asm volatile("s_waitcnt vmcnt(0)" ::: "memory");
    BARR();
    RD_A(buf, 1);
    RD_B(buf, 0);
    MM(1, 0);
    BARR();
    RD_B(buf, 1);
    MM(1, 1);
  }
#undef STAGE_A
#undef STAGE_B
#undef RD_A
#undef RD_B
#undef MM
#undef BARR
#undef VW4

  const int m0 = tm * 256 + wm * 128;
  const int e0 = (tn & 3) * 256 + wn * 64;
  const int sel = tn >> 2;  // 0:Q 1:K 2:V
  if (sel == 2) {           // V swapped: acc = C^T
#pragma unroll
    for (int mi = 0; mi < 8; ++mi)
#pragma unroll
      for (int ni = 0; ni < 4; ++ni)
#pragma unroll
        for (int ii = 0; ii < 4; ++ii) {
          const int e = e0 + ni * 16 + lh * 4 + ii;
          const int m = m0 + mi * 16 + lr;
          const int b = m >> 11, n = m & (S_LEN - 1);
          const int h = e >> 6, d = e & (HDIM - 1);
          (outb + 2 * XN)[((size_t)((b * NHEAD + h) * HDIM + d)) * S_LEN + n] =
              f2bf(acc[mi][ni][ii]);
        }
  } else {
#pragma unroll
    for (int mi = 0; mi < 8; ++mi)
#pragma unroll
      for (int ni = 0; ni < 4; ++ni)
#pragma unroll
        for (int ii = 0; ii < 4; ++ii) {
          const int m = m0 + mi * 16 + lh * 4 + ii;
          const int e = e0 + ni * 16 + lr;
          const int b = m >> 11, n = m & (S_LEN - 1);
          const int h = e >> 6, d = e & (HDIM - 1);
          if (sel == 0)
            outb[((size_t)((b * NHEAD + h) * S_LEN + n)) * HDIM + d] =
                f2bf(acc[mi][ni][ii] * QSCALE);
          else
            (outb + XN)[((size_t)((b * NHEAD + h) * S_LEN + n)) * HDIM + d] =
                f2bf(acc[mi][ni][ii]);
        }
  }
}

// ---------------- out-proj GEMM (R18-proven): 64x64 tile -> 1024 blocks ----------------
__global__ __launch_bounds__(256) void gemm_out(const short* __restrict__ A,
                                                const short* __restrict__ Bt,
                                                float* __restrict__ outf,
                                                const float* __restrict__ bias) {
  constexpr int K = DMODEL;
  constexpr int N = DMODEL;
  __shared__ short As[2][64 * 64];  // 8KB x2
  __shared__ short Bs[2][64 * 64];  // 8KB x2
  const int tid = threadIdx.x;
  const int w = tid >> 6, l = tid & 63;
  const int lr = l & 15, lh = l >> 4;
  const int wr = w >> 1, wc = w & 1;
  const int tm = blockIdx.x, tn = blockIdx.y;

  const int srow = tid >> 3;  // 0..31
  const int ssl = tid & 7;
  const int ssg = ssl ^ (srow & 7);

  f32x4 acc[2][2] = {};

#define OSTAGE(KT, BUF)                                                             \
  {                                                                                 \
    _Pragma("unroll") for (int i = 0; i < 2; ++i) {                                 \
      const int row = i * 32 + srow;                                                \
      GLL16(A + (size_t)(tm * 64 + row) * K + (KT)*64 + ssg * 8,                    \
            &As[BUF][(i * 256 + w * 64) * 8]);                                      \
    }                                                                               \
    _Pragma("unroll") for (int i = 0; i < 2; ++i) {                                 \
      const int row = i * 32 + srow;                                                \
      GLL16(Bt + (size_t)(tn * 64 + row) * K + (KT)*64 + ssg * 8,                   \
            &Bs[BUF][(i * 256 + w * 64) * 8]);                                      \
    }                                                                               \
  }

  OSTAGE(0, 0);
  asm volatile("s_waitcnt vmcnt(0)" ::: "memory");
  __syncthreads();

  for (int kt = 0; kt < K / 64; ++kt) {
    const int buf = kt & 1;
    if (kt < K / 64 - 1) OSTAGE(kt + 1, buf ^ 1);

#pragma unroll
    for (int kh = 0; kh < 2; ++kh) {
      bf16x8 af[2], bfr[2];
#pragma unroll
      for (int mi = 0; mi < 2; ++mi) {
        const int row = wr * 32 + mi * 16 + lr;
        af[mi] = *(const bf16x8*)&As[buf][row * 64 + 8 * ((kh * 4 + lh) ^ (row & 7))];
      }
#pragma unroll
      for (int ni = 0; ni < 2; ++ni) {
        const int row = wc * 32 + ni * 16 + lr;
        bfr[ni] = *(const bf16x8*)&Bs[buf][row * 64 + 8 * ((kh * 4 + lh) ^ (row & 7))];
      }
#pragma unroll
      for (int mi = 0; mi < 2; ++mi)
#pragma unroll
        for (int ni = 0; ni < 2; ++ni)
          acc[mi][ni] = MFMA16(af[mi], bfr[ni], acc[mi][ni]);
    }

    asm volatile("s_waitcnt vmcnt(0)" ::: "memory");
    __syncthreads();
  }
#undef OSTAGE

#pragma unroll
  for (int mi = 0; mi < 2; ++mi)
#pragma unroll
    for (int ni = 0; ni < 2; ++ni)
#pragma unroll
      for (int i = 0; i < 2 * 2; ++i) {
        const int m = tm * 64 + wr * 32 + mi * 16 + lh * 4 + i;
        const int e = tn * 64 + wc * 32 + ni * 16 + lr;
        outf[(size_t)m * N + e] = acc[mi][ni][i] + bias[e];
      }
}

// ---- flash attention (R19-proven) + R23 staging address strength-reduction.
// K: R&7 == r8 for all staged rows -> swizzle slot sg = sc^r8 is loop-invariant;
// one hoisted lane base + 4KB/tile bump + {0,1,2,3}KB imm offsets. V: 4 hoisted
// lane pointers bumped 64B/tile. Identical LDS image to R19/R22.
__global__ __launch_bounds__(256) void attn_kernel(const short* __restrict__ Qg,
                                                   const short* __restrict__ Kg,
                                                   const short* __restrict__ Vg,
                                                   short* __restrict__ ctx) {
  __shared__ alignas(16) short KV[4][8192];  // per wave: K dbuf 2x2048 | V dbuf 2x2048
  __shared__ float mls[4][2][32];
  const int tidx = threadIdx.x;
  const int s = tidx >> 6;  // wave 0..3
  const int l = tidx & 63;
  const int lq = l & 31;
  const int h5 = l >> 5;
  const int bid = blockIdx.x;
  const int xcd = bid & 7;
  const int j = bid >> 3;             // 0..127 per-XCD stream index
  const int bh = xcd * 4 + (j >> 5);  // 4 heads per XCD -> K/V L2-resident
  const int qc = 31 - (j & 31);       // big chunks first (LPT under queueing)
  const int qbase = qc * 64;
  const short* Qh = Qg + (size_t)bh * (S_LEN * HDIM);
  const short* Kh = Kg + (size_t)bh * (S_LEN * HDIM);
  const short* Vh = Vg + (size_t)bh * (HDIM * S_LEN);

  short* Kbase = &KV[s][0];
  short* Vbase = &KV[s][4096];
  const int r8 = l >> 3;
  const int sc = l & 7;
  const int sg = sc ^ r8;  // loop-invariant swizzle slot (R&7 == r8 for all i)

  bf16x8 qf0[4], qf1[4];
#pragma unroll
  for (int cc = 0; cc < 4; ++cc) {
    qf0[cc] = *(const bf16x8*)&Qh[(size_t)(qbase + lq) * HDIM + cc * 16 + h5 * 8];
    qf1[cc] = *(const bf16x8*)&Qh[(size_t)(qbase + 32 + lq) * HDIM + cc * 16 + h5 * 8];
  }

  f32x16 o00 = {}, o01 = {}, o10 = {}, o11 = {};
  float ll0 = 0.f, ll1 = 0.f;

  const int ntot = 2 * qc + 2;
  const int td0 = 2 * qc, td1 = 2 * qc + 1;
  const int ts = (ntot * s) >> 2;
  const int te = (ntot * (s + 1)) >> 2;

  // hoisted staging lane pointers (bumped per staged tile)
  const short* kp = Kh + (size_t)(ts * 32 + r8) * HDIM + sg * 8;
  const short* vp0 = Vh + (size_t)(2 * r8 + (sg >> 2)) * S_LEN + ts * 32 + (sg & 3) * 8;
  const short* vp1 = vp0 + 16 * S_LEN;
  const short* vp2 = vp0 + 32 * S_LEN;
  const short* vp3 = vp0 + 48 * S_LEN;

#define STAGE(BUF)                                          \
  {                                                         \
    GLL16(kp, &Kbase[(BUF)*2048]);                          \
    GLL16(kp + 512, &Kbase[(BUF)*2048 + 512]);              \
    GLL16(kp + 1024, &Kbase[(BUF)*2048 + 1024]);            \
    GLL16(kp + 1536, &Kbase[(BUF)*2048 + 1536]);            \
    GLL16(vp0, &Vbase[(BUF)*2048]);                         \
    GLL16(vp1, &Vbase[(BUF)*2048 + 512]);                   \
    GLL16(vp2, &Vbase[(BUF)*2048 + 1024]);                  \
    GLL16(vp3, &Vbase[(BUF)*2048 + 1536]);                  \
    kp += 32 * HDIM;                                        \
    vp0 += 32;                                              \
    vp1 += 32;                                              \
    vp2 += 32;                                              \
    vp3 += 32;                                              \
  }

  if (ts < te) STAGE(0);

  for (int t = ts; t < te; ++t) {
    const int buf = (t - ts) & 1;
    if (t + 1 < te) {
      STAGE(buf ^ 1);
      asm volatile("s_waitcnt vmcnt(8)" ::: "memory");
    } else {
      asm volatile("s_waitcnt vmcnt(0)" ::: "memory");
    }
    const short* Ksb = &Kbase[buf * 2048];
    const short* Vsb = &Vbase[buf * 2048];

    bf16x8 kf[4];
#pragma unroll
    for (int cc = 0; cc < 4; ++cc)
      kf[cc] = *(const bf16x8*)&Ksb[lq * 64 + 8 * ((cc * 2 + h5) ^ (lq & 7))];
    const int R0 = lq >> 1, p0 = (lq & 1) * 4 + h5;
    const int R1 = 16 + (lq >> 1);
    const bf16x8 v00 = *(const bf16x8*)&Vsb[R0 * 64 + 8 * ((p0 + 0) ^ (R0 & 7))];
    const bf16x8 v01 = *(const bf16x8*)&Vsb[R0 * 64 + 8 * ((p0 + 2) ^ (R0 & 7))];
    const bf16x8 v10 = *(const bf16x8*)&Vsb[R1 * 64 + 8 * ((p0 + 0) ^ (R1 & 7))];
    const bf16x8 v11 = *(const bf16x8*)&Vsb[R1 * 64 + 8 * ((p0 + 2) ^ (R1 & 7))];

    f32x16 st0 = {}, st1 = {};
    __builtin_amdgcn_s_setprio(1);
#pragma unroll
    for (int cc = 0; cc < 4; ++cc) {
      st0 = MFMA32(kf[cc], qf0[cc], st0);
      st1 = MFMA32(kf[cc], qf1[cc], st1);
    }
    __builtin_amdgcn_s_setprio(0);

    if (t == td0) {  // half0 diagonal
#pragma unroll
      for (int rr = 0; rr < 16; ++rr) {
        const int crow = (rr & 3) + 8 * (rr >> 2) + 4 * h5;
        if (crow > lq) st0[rr] = -__builtin_inff();
      }
    } else if (t == td1) {  // half0 fully masked; half1 diagonal
#pragma unroll
      for (int rr = 0; rr < 16; ++rr) {
        st0[rr] = -__builtin_inff();
        const int crow = (rr & 3) + 8 * (rr >> 2) + 4 * h5;
        if (crow > lq) st1[rr] = -__builtin_inff();
      }
    }

#pragma unroll
    for (int rr = 0; rr < 16; ++rr) st0[rr] = __builtin_amdgcn_exp2f(st0[rr]);
#pragma unroll
    for (int rr = 0; rr < 16; ++rr) st1[rr] = __builtin_amdgcn_exp2f(st1[rr]);
    {
      const float a = ((st0[0] + st0[1]) + (st0[2] + st0[3])) +
                      ((st0[4] + st0[5]) + (st0[6] + st0[7]));
      const float b = ((st0[8] + st0[9]) + (st0[10] + st0[11])) +
                      ((st0[12] + st0[13]) + (st0[14] + st0[15]));
      ll0 += a + b;
      const float c = ((st1[0] + st1[1]) + (st1[2] + st1[3])) +
                      ((st1[4] + st1[5]) + (st1[6] + st1[7]));
      const float d = ((st1[8] + st1[9]) + (st1[10] + st1[11])) +
                      ((st1[12] + st1[13]) + (st1[14] + st1[15]));
      ll1 += c + d;
    }

    unsigned a0 = cvt_pk_bf16(st0[0], st0[1]), b0 = cvt_pk_bf16(st0[4], st0[5]);
    unsigned a1 = cvt_pk_bf16(st0[2], st0[3]), b1 = cvt_pk_bf16(st0[6], st0[7]);
    unsigned a2 = cvt_pk_bf16(st0[8], st0[9]), b2 = cvt_pk_bf16(st0[12], st0[13]);
    unsigned a3 = cvt_pk_bf16(st0[10], st0[11]), b3 = cvt_pk_bf16(st0[14], st0[15]);
    unsigned c0 = cvt_pk_bf16(st1[0], st1[1]), d0 = cvt_pk_bf16(st1[4], st1[5]);
    unsigned c1 = cvt_pk_bf16(st1[2], st1[3]), d1 = cvt_pk_bf16(st1[6], st1[7]);
    unsigned c2 = cvt_pk_bf16(st1[8], st1[9]), d2 = cvt_pk_bf16(st1[12], st1[13]);
    unsigned c3 = cvt_pk_bf16(st1[10], st1[11]), d3 = cvt_pk_bf16(st1[14], st1[15]);
    swap32(a0, b0);
    swap32(a1, b1);
    swap32(a2, b2);
    swap32(a3, b3);
    swap32(c0, d0);
    swap32(c1, d1);
    swap32(c2, d2);
    swap32(c3, d3);
    const u32x4 pwA0 = {a0, a1, b0, b1};
    const u32x4 pwA1 = {a2, a3, b2, b3};
    const u32x4 pwB0 = {c0, c1, d0, d1};
    const u32x4 pwB1 = {c2, c3, d2, d3};
    const bf16x8 pa0 = __builtin_bit_cast(bf16x8, pwA0);
    const bf16x8 pa1 = __builtin_bit_cast(bf16x8, pwA1);
    const bf16x8 pb0 = __builtin_bit_cast(bf16x8, pwB0);
    const bf16x8 pb1 = __builtin_bit_cast(bf16x8, pwB1);

    __builtin_amdgcn_s_setprio(1);
    o00 = MFMA32(pa0, v00, o00);
    o10 = MFMA32(pb0, v00, o10);
    o01 = MFMA32(pa0, v10, o01);
    o11 = MFMA32(pb0, v10, o11);
    o00 = MFMA32(pa1, v01, o00);
    o10 = MFMA32(pb1, v01, o10);
    o01 = MFMA32(pa1, v11, o01);
    o11 = MFMA32(pb1, v11, o11);
    __builtin_amdgcn_s_setprio(0);
  }
#undef STAGE

  float* me = (float*)&KV[s][0];  // 4096 floats
#pragma unroll
  for (int rr = 0; rr < 16; ++rr) {
    const int crow = (rr & 3) + 8 * (rr >> 2) + 4 * h5;
    me[crow * 64 + lq] = o00[rr];
    me[crow * 64 + 32 + lq] = o01[rr];
    me[(32 + crow) * 64 + lq] = o10[rr];
    me[(32 + crow) * 64 + 32 + lq] = o11[rr];
  }
  ll0 += __shfl_xor(ll0, 32);
  ll1 += __shfl_xor(ll1, 32);
  if (h5 == 0) {
    mls[s][0][lq] = ll0;
    mls[s][1][lq] = ll1;
  }
  __syncthreads();

  const float* om = (const float*)&KV[0][0];  // wave stride 4096 floats
  const int b = bh >> 4, h = bh & (NHEAD - 1);
  const int r2 = tidx >> 2;        // q-row 0..63
  const int d0 = (tidx & 3) * 16;  // d group (16 elems)
  const float lsum = mls[0][r2 >> 5][r2 & 31] + mls[1][r2 >> 5][r2 & 31] +
                     mls[2][r2 >> 5][r2 & 31] + mls[3][r2 >> 5][r2 & 31];
  const float inv = __builtin_amdgcn_rcpf(lsum);
  const size_t base = (size_t)(b * S_LEN + qbase + r2) * DMODEL + h * HDIM + d0;
#pragma unroll
  for (int i = 0; i < 16; ++i) {
    const int o = r2 * 64 + d0 + i;
    const float v = om[o] + om[4096 + o] + om[8192 + o] + om[12288 + o];
    ctx[base + i] = f2bf(v * inv);
  }
}

extern "C" void kernel_launch(void* const* d_in, const int* in_sizes, int n_in,
                              void* d_out, int out_size, void* d_ws, size_t ws_size,
                              hipStream_t stream) {
  const float* x = (const float*)d_in[0];
  const float* Wq = (const float*)d_in[1];
  const float* Wk = (const float*)d_in[2];
  const float* Wv = (const float*)d_in[3];
  const float* Wo = (const float*)d_in[4];
  const float* bo = (const float*)d_in[5];

  const size_t XN = (size_t)MROWS * DMODEL;   // 4096*1024
  const size_t WN = (size_t)DMODEL * DMODEL;  // 1024*1024

  short* ws = (short*)d_ws;
  short* xb = ws;
  short* Wqb = xb + XN;  // Wq,Wk,Wv,Wo contiguous ([3072+1024][1024])
  short* Wob = Wqb + 3 * WN;
  short* Qb = Wob + WN;  // Q,K,V contiguous
  short* Kb = Qb + XN;
  short* Vb = Kb + XN;
  short* ctxb = Vb + XN;
  if (ws_size < (5 * XN + 4 * WN) * sizeof(short)) return;

  cvt_all<<<2048, 256, 0, stream>>>(x, Wq, Wk, Wv, Wo, xb);

  gemm_qkv8<<<dim3(MROWS / 256, 3 * DMODEL / 256), 512, 0, stream>>>(xb, Wqb, Qb);

  attn_kernel<<<1024, 256, 0, stream>>>(Qb, Kb, Vb, ctxb);

  gemm_out<<<dim3(MROWS / 64, DMODEL / 64), 256, 0, stream>>>(ctxb, Wob, (float*)d_out,
                                                              bo);
}

// Round 24
// 113.407 us; speedup vs baseline: 1.0708x; 1.0708x over previous
//
#include <hip/hip_runtime.h>

#define DEV __device__ __forceinline__

typedef __bf16 bf16x8 __attribute__((ext_vector_type(8)));
typedef float f32x4 __attribute__((ext_vector_type(4)));
typedef float f32x16 __attribute__((ext_vector_type(16)));
typedef unsigned u32x4 __attribute__((ext_vector_type(4)));

constexpr int S_LEN = 2048;
constexpr int DMODEL = 1024;
constexpr int NHEAD = 16;
constexpr int HDIM = 64;
constexpr int BATCH = 2;
constexpr int MROWS = BATCH * S_LEN;  // 4096
constexpr float QSCALE = 0.125f * 1.44269504088896f;  // 1/sqrt(64) * log2(e)

DEV short f2bf(float x) {
  unsigned u = __builtin_bit_cast(unsigned, x);
  unsigned r = u + 0x7fffu + ((u >> 16) & 1u);
  return (short)(r >> 16);
}

#define MFMA16(a, b, c) __builtin_amdgcn_mfma_f32_16x16x32_bf16((a), (b), (c), 0, 0, 0)
#define MFMA32(a, b, c) __builtin_amdgcn_mfma_f32_32x32x16_bf16((a), (b), (c), 0, 0, 0)
#define GLL16(g, l)                                                                     \
  __builtin_amdgcn_global_load_lds((const __attribute__((address_space(1))) void*)(g),  \
                                   (__attribute__((address_space(3))) void*)(l), 16, 0, 0)

DEV unsigned cvt_pk_bf16(float a, float b) {
  unsigned r;
  asm("v_cvt_pk_bf16_f32 %0, %1, %2" : "=v"(r) : "v"(a), "v"(b));
  return r;
}
DEV void swap32(unsigned& a, unsigned& b) {
  asm("v_permlane32_swap_b32 %0, %1" : "+v"(a), "+v"(b));
}

// ---------------- fused fp32 -> bf16 convert: [x | Wq | Wk | Wv | Wo] ----------------
__global__ void cvt_all(const float* __restrict__ x, const float* __restrict__ wq,
                        const float* __restrict__ wk, const float* __restrict__ wv,
                        const float* __restrict__ wo, short* __restrict__ out) {
  const size_t XNe = (size_t)MROWS * DMODEL;   // 4M
  const size_t WNe = (size_t)DMODEL * DMODEL;  // 1M = 2^20
  const size_t tot = XNe + 4 * WNe;
  size_t i = ((size_t)blockIdx.x * blockDim.x + threadIdx.x) * 4;
  const size_t stride = (size_t)gridDim.x * blockDim.x * 4;
  for (; i < tot; i += stride) {
    const float* src;
    size_t off;
    if (i < XNe) {
      src = x;
      off = i;
    } else {
      const size_t k = i - XNe;
      const int seg = (int)(k >> 20);
      off = k & (WNe - 1);
      src = seg == 0 ? wq : seg == 1 ? wk : seg == 2 ? wv : wo;
    }
    float4 v = *(const float4*)&src[off];
    short4 r;
    r.x = f2bf(v.x);
    r.y = f2bf(v.y);
    r.z = f2bf(v.z);
    r.w = f2bf(v.w);
    *(short4*)&out[i] = r;
  }
}

// ------------- QKV GEMM, 8-phase 256x256 (T3+T4): BK=64, 8 waves, 128KB LDS ----------
__global__ __launch_bounds__(512) void gemm_qkv8(const short* __restrict__ A,
                                                 const short* __restrict__ Bt,
                                                 short* __restrict__ outb) {
  constexpr int K = DMODEL;
  constexpr int NT = K / 64;  // 16
  constexpr size_t XN = (size_t)MROWS * DMODEL;
  __shared__ short Alds[2][256 * 64];  // 64KB
  __shared__ short Blds[2][256 * 64];  // 64KB
  const int tid = threadIdx.x;
  const int w = tid >> 6, l = tid & 63;
  const int lr = l & 15, lh = l >> 4;  // lh 0..3
  const int wm = w >> 2, wn = w & 3;   // wave tile: rows wm*128, cols wn*64
  const int tm = blockIdx.x, tn = blockIdx.y;
  const bool vswap = (tn >= 8);

  const int l3 = l >> 3;                // 0..7
  const int scol = ((l & 7) ^ l3) * 8;  // pre-swizzled global col (row&7 == l3)

  f32x4 acc[8][4] = {};
  bf16x8 af[8], bfv[4];

#define STAGE_A(KT2, NB, H)                                                   \
  {                                                                           \
    _Pragma("unroll") for (int i = 0; i < 2; ++i) {                           \
      const int r = w * 8 + l3 + i * 128 + (H)*64;                            \
      GLL16(A + (size_t)(tm * 256 + r) * K + (KT2)*64 + scol,                 \
            &Alds[NB][(i * 1024 + (H)*512 + w * 64) * 8]);                    \
    }                                                                         \
  }
#define STAGE_B(KT2, NB, J)                                                   \
  {                                                                           \
    _Pragma("unroll") for (int i = 0; i < 2; ++i) {                           \
      const int g = i * 2 + (w >> 2);                                         \
      const int r = g * 64 + (J)*32 + (w & 3) * 8 + l3;                       \
      GLL16(Bt + (size_t)(tn * 256 + r) * K + (KT2)*64 + scol,                \
            &Blds[NB][(g * 512 + (J)*256 + (w & 3) * 64) * 8]);               \
    }                                                                         \
  }

#define RD_A(BUF, MH)                                                          \
  _Pragma("unroll") for (int mi = 0; mi < 4; ++mi) {                           \
    const int r = wm * 128 + (MH)*64 + mi * 16 + lr;                           \
    af[mi * 2 + 0] = *(const bf16x8*)&Alds[BUF][r * 64 + 8 * (lh ^ (r & 7))];  \
    af[mi * 2 + 1] =                                                           \
        *(const bf16x8*)&Alds[BUF][r * 64 + 8 * ((4 + lh) ^ (r & 7))];         \
  }
#define RD_B(BUF, NH)                                                          \
  _Pragma("unroll") for (int ni = 0; ni < 2; ++ni) {                           \
    const int r = wn * 64 + (NH)*32 + ni * 16 + lr;                            \
    bfv[ni * 2 + 0] = *(const bf16x8*)&Blds[BUF][r * 64 + 8 * (lh ^ (r & 7))]; \
    bfv[ni * 2 + 1] =                                                          \
        *(const bf16x8*)&Blds[BUF][r * 64 + 8 * ((4 + lh) ^ (r & 7))];         \
  }

#define MM(MH, NH)                                                              \
  {                                                                             \
    __builtin_amdgcn_s_setprio(1);                                              \
    if (!vswap) {                                                               \
      _Pragma("unroll") for (int ks = 0; ks < 2; ++ks)                          \
      _Pragma("unroll") for (int mi = 0; mi < 4; ++mi)                          \
      _Pragma("unroll") for (int ni = 0; ni < 2; ++ni)                          \
          acc[(MH)*4 + mi][(NH)*2 + ni] = MFMA16(                               \
              af[mi * 2 + ks], bfv[ni * 2 + ks], acc[(MH)*4 + mi][(NH)*2 + ni]);\
    } else {                                                                    \
      _Pragma("unroll") for (int ks = 0; ks < 2; ++ks)                          \
      _Pragma("unroll") for (int mi = 0; mi < 4; ++mi)                          \
      _Pragma("unroll") for (int ni = 0; ni < 2; ++ni)                          \
          acc[(MH)*4 + mi][(NH)*2 + ni] = MFMA16(                               \
              bfv[ni * 2 + ks], af[mi * 2 + ks], acc[(MH)*4 + mi][(NH)*2 + ni]);\
    }                                                                           \
    __builtin_amdgcn_s_setprio(0);                                              \
  }

#define BARR()                       \
  __builtin_amdgcn_s_barrier();      \
  asm volatile("" ::: "memory")
#define VW4() asm volatile("s_waitcnt vmcnt(4)" ::: "memory")

  STAGE_A(0, 0, 0);
  STAGE_B(0, 0, 0);
  STAGE_B(0, 0, 1);
  STAGE_A(0, 0, 1);

  for (int kt = 0; kt < NT - 1; ++kt) {
    const int buf = kt & 1, nb = buf ^ 1;
    VW4();
    BARR();
    RD_A(buf, 0);
    RD_B(buf, 0);
    STAGE_A(kt + 1, nb, 0);
    MM(0, 0);
    VW4();
    BARR();
    RD_B(buf, 1);
    STAGE_B(kt + 1, nb, 0);
    MM(0, 1);
    VW4();
    BARR();
    RD_A(buf, 1);
    RD_B(buf, 0);
    STAGE_B(kt + 1, nb, 1);
    MM(1, 0);
    BARR();
    RD_B(buf, 1);
    STAGE_A(kt + 1, nb, 1);
    MM(1, 1);
  }
  {  // peeled last tile
    const int buf = (NT - 1) & 1;
    VW4();
    BARR();
    RD_A(buf, 0);
    RD_B(buf, 0);
    MM(0, 0);
    asm volatile("s_waitcnt vmcnt(2)" ::: "memory");
    BARR();
    RD_B(buf, 1);
    MM(0, 1);
    asm volatile("s_waitcnt vmcnt(0)" ::: "memory");
    BARR();
    RD_A(buf, 1);
    RD_B(buf, 0);
    MM(1, 0);
    BARR();
    RD_B(buf, 1);
    MM(1, 1);
  }
#undef STAGE_A
#undef STAGE_B
#undef RD_A
#undef RD_B
#undef MM
#undef BARR
#undef VW4

  const int m0 = tm * 256 + wm * 128;
  const int e0 = (tn & 3) * 256 + wn * 64;
  const int sel = tn >> 2;  // 0:Q 1:K 2:V
  if (sel == 2) {           // V swapped: acc = C^T
#pragma unroll
    for (int mi = 0; mi < 8; ++mi)
#pragma unroll
      for (int ni = 0; ni < 4; ++ni)
#pragma unroll
        for (int ii = 0; ii < 4; ++ii) {
          const int e = e0 + ni * 16 + lh * 4 + ii;
          const int m = m0 + mi * 16 + lr;
          const int b = m >> 11, n = m & (S_LEN - 1);
          const int h = e >> 6, d = e & (HDIM - 1);
          (outb + 2 * XN)[((size_t)((b * NHEAD + h) * HDIM + d)) * S_LEN + n] =
              f2bf(acc[mi][ni][ii]);
        }
  } else {
#pragma unroll
    for (int mi = 0; mi < 8; ++mi)
#pragma unroll
      for (int ni = 0; ni < 4; ++ni)
#pragma unroll
        for (int ii = 0; ii < 4; ++ii) {
          const int m = m0 + mi * 16 + lh * 4 + ii;
          const int e = e0 + ni * 16 + lr;
          const int b = m >> 11, n = m & (S_LEN - 1);
          const int h = e >> 6, d = e & (HDIM - 1);
          if (sel == 0)
            outb[((size_t)((b * NHEAD + h) * S_LEN + n)) * HDIM + d] =
                f2bf(acc[mi][ni][ii] * QSCALE);
          else
            (outb + XN)[((size_t)((b * NHEAD + h) * S_LEN + n)) * HDIM + d] =
                f2bf(acc[mi][ni][ii]);
        }
  }
}

// ---------------- out-proj GEMM (R18-proven): 64x64 tile -> 1024 blocks ----------------
__global__ __launch_bounds__(256) void gemm_out(const short* __restrict__ A,
                                                const short* __restrict__ Bt,
                                                float* __restrict__ outf,
                                                const float* __restrict__ bias) {
  constexpr int K = DMODEL;
  constexpr int N = DMODEL;
  __shared__ short As[2][64 * 64];  // 8KB x2
  __shared__ short Bs[2][64 * 64];  // 8KB x2
  const int tid = threadIdx.x;
  const int w = tid >> 6, l = tid & 63;
  const int lr = l & 15, lh = l >> 4;
  const int wr = w >> 1, wc = w & 1;
  const int tm = blockIdx.x, tn = blockIdx.y;

  const int srow = tid >> 3;  // 0..31
  const int ssl = tid & 7;
  const int ssg = ssl ^ (srow & 7);

  f32x4 acc[2][2] = {};

#define OSTAGE(KT, BUF)                                                             \
  {                                                                                 \
    _Pragma("unroll") for (int i = 0; i < 2; ++i) {                                 \
      const int row = i * 32 + srow;                                                \
      GLL16(A + (size_t)(tm * 64 + row) * K + (KT)*64 + ssg * 8,                    \
            &As[BUF][(i * 256 + w * 64) * 8]);                                      \
    }                                                                               \
    _Pragma("unroll") for (int i = 0; i < 2; ++i) {                                 \
      const int row = i * 32 + srow;                                                \
      GLL16(Bt + (size_t)(tn * 64 + row) * K + (KT)*64 + ssg * 8,                   \
            &Bs[BUF][(i * 256 + w * 64) * 8]);                                      \
    }                                                                               \
  }

  OSTAGE(0, 0);
  asm volatile("s_waitcnt vmcnt(0)" ::: "memory");
  __syncthreads();

  for (int kt = 0; kt < K / 64; ++kt) {
    const int buf = kt & 1;
    if (kt < K / 64 - 1) OSTAGE(kt + 1, buf ^ 1);

#pragma unroll
    for (int kh = 0; kh < 2; ++kh) {
      bf16x8 af[2], bfr[2];
#pragma unroll
      for (int mi = 0; mi < 2; ++mi) {
        const int row = wr * 32 + mi * 16 + lr;
        af[mi] = *(const bf16x8*)&As[buf][row * 64 + 8 * ((kh * 4 + lh) ^ (row & 7))];
      }
#pragma unroll
      for (int ni = 0; ni < 2; ++ni) {
        const int row = wc * 32 + ni * 16 + lr;
        bfr[ni] = *(const bf16x8*)&Bs[buf][row * 64 + 8 * ((kh * 4 + lh) ^ (row & 7))];
      }
#pragma unroll
      for (int mi = 0; mi < 2; ++mi)
#pragma unroll
        for (int ni = 0; ni < 2; ++ni)
          acc[mi][ni] = MFMA16(af[mi], bfr[ni], acc[mi][ni]);
    }

    asm volatile("s_waitcnt vmcnt(0)" ::: "memory");
    __syncthreads();
  }
#undef OSTAGE

#pragma unroll
  for (int mi = 0; mi < 2; ++mi)
#pragma unroll
    for (int ni = 0; ni < 2; ++ni)
#pragma unroll
      for (int i = 0; i < 2 * 2; ++i) {
        const int m = tm * 64 + wr * 32 + mi * 16 + lh * 4 + i;
        const int e = tn * 64 + wc * 32 + ni * 16 + lr;
        outf[(size_t)m * N + e] = acc[mi][ni][i] + bias[e];
      }
}

// ---- flash attention (R19-proven): 64 q-rows/wave, branchless interleaved dual-half,
// 4-way KV-split, dbuf K+V LDS, m==0 softmax, sum-merge over own 16KB region.
__global__ __launch_bounds__(256) void attn_kernel(const short* __restrict__ Qg,
                                                   const short* __restrict__ Kg,
                                                   const short* __restrict__ Vg,
                                                   short* __restrict__ ctx) {
  __shared__ alignas(16) short KV[4][8192];  // per wave: K dbuf 2x2048 | V dbuf 2x2048
  __shared__ float mls[4][2][32];
  const int tidx = threadIdx.x;
  const int s = tidx >> 6;  // wave 0..3
  const int l = tidx & 63;
  const int lq = l & 31;
  const int h5 = l >> 5;
  const int bid = blockIdx.x;
  const int xcd = bid & 7;
  const int j = bid >> 3;             // 0..127 per-XCD stream index
  const int bh = xcd * 4 + (j >> 5);  // 4 heads per XCD -> K/V L2-resident
  const int qc = 31 - (j & 31);       // big chunks first (LPT under queueing)
  const int qbase = qc * 64;
  const short* Qh = Qg + (size_t)bh * (S_LEN * HDIM);
  const short* Kh = Kg + (size_t)bh * (S_LEN * HDIM);
  const short* Vh = Vg + (size_t)bh * (HDIM * S_LEN);

  short* Kbase = &KV[s][0];
  short* Vbase = &KV[s][4096];
  const int r8 = l >> 3;
  const int sc = l & 7;

  bf16x8 qf0[4], qf1[4];
#pragma unroll
  for (int cc = 0; cc < 4; ++cc) {
    qf0[cc] = *(const bf16x8*)&Qh[(size_t)(qbase + lq) * HDIM + cc * 16 + h5 * 8];
    qf1[cc] = *(const bf16x8*)&Qh[(size_t)(qbase + 32 + lq) * HDIM + cc * 16 + h5 * 8];
  }

  f32x16 o00 = {}, o01 = {}, o10 = {}, o11 = {};
  float ll0 = 0.f, ll1 = 0.f;

  const int ntot = 2 * qc + 2;
  const int td0 = 2 * qc, td1 = 2 * qc + 1;
  const int ts = (ntot * s) >> 2;
  const int te = (ntot * (s + 1)) >> 2;

#define STAGE(T, BUF)                                                              \
  {                                                                                \
    _Pragma("unroll") for (int i = 0; i < 4; ++i) {                                \
      const int R = i * 8 + r8;                                                    \
      const int sg = sc ^ (R & 7);                                                 \
      GLL16(Kh + (size_t)((T)*32 + R) * HDIM + sg * 8,                             \
            &Kbase[(BUF)*2048 + i * 512]);                                         \
      GLL16(Vh + (size_t)(2 * R + (sg >> 2)) * S_LEN + (T)*32 + (sg & 3) * 8,      \
            &Vbase[(BUF)*2048 + i * 512]);                                         \
    }                                                                              \
  }

  if (ts < te) STAGE(ts, 0);

  for (int t = ts; t < te; ++t) {
    const int buf = (t - ts) & 1;
    if (t + 1 < te) {
      STAGE(t + 1, buf ^ 1);
      asm volatile("s_waitcnt vmcnt(8)" ::: "memory");
    } else {
      asm volatile("s_waitcnt vmcnt(0)" ::: "memory");
    }
    const short* Ksb = &Kbase[buf * 2048];
    const short* Vsb = &Vbase[buf * 2048];

    bf16x8 kf[4];
#pragma unroll
    for (int cc = 0; cc < 4; ++cc)
      kf[cc] = *(const bf16x8*)&Ksb[lq * 64 + 8 * ((cc * 2 + h5) ^ (lq & 7))];
    const int R0 = lq >> 1, p0 = (lq & 1) * 4 + h5;
    const int R1 = 16 + (lq >> 1);
    const bf16x8 v00 = *(const bf16x8*)&Vsb[R0 * 64 + 8 * ((p0 + 0) ^ (R0 & 7))];
    const bf16x8 v01 = *(const bf16x8*)&Vsb[R0 * 64 + 8 * ((p0 + 2) ^ (R0 & 7))];
    const bf16x8 v10 = *(const bf16x8*)&Vsb[R1 * 64 + 8 * ((p0 + 0) ^ (R1 & 7))];
    const bf16x8 v11 = *(const bf16x8*)&Vsb[R1 * 64 + 8 * ((p0 + 2) ^ (R1 & 7))];

    f32x16 st0 = {}, st1 = {};
    __builtin_amdgcn_s_setprio(1);
#pragma unroll
    for (int cc = 0; cc < 4; ++cc) {
      st0 = MFMA32(kf[cc], qf0[cc], st0);
      st1 = MFMA32(kf[cc], qf1[cc], st1);
    }
    __builtin_amdgcn_s_setprio(0);

    if (t == td0) {  // half0 diagonal
#pragma unroll
      for (int rr = 0; rr < 16; ++rr) {
        const int crow = (rr & 3) + 8 * (rr >> 2) + 4 * h5;
        if (crow > lq) st0[rr] = -__builtin_inff();
      }
    } else if (t == td1) {  // half0 fully masked; half1 diagonal
#pragma unroll
      for (int rr = 0; rr < 16; ++rr) {
        st0[rr] = -__builtin_inff();
        const int crow = (rr & 3) + 8 * (rr >> 2) + 4 * h5;
        if (crow > lq) st1[rr] = -__builtin_inff();
      }
    }

#pragma unroll
    for (int rr = 0; rr < 16; ++rr) st0[rr] = __builtin_amdgcn_exp2f(st0[rr]);
#pragma unroll
    for (int rr = 0; rr < 16; ++rr) st1[rr] = __builtin_amdgcn_exp2f(st1[rr]);
    {
      const float a = ((st0[0] + st0[1]) + (st0[2] + st0[3])) +
                      ((st0[4] + st0[5]) + (st0[6] + st0[7]));
      const float b = ((st0[8] + st0[9]) + (st0[10] + st0[11])) +
                      ((st0[12] + st0[13]) + (st0[14] + st0[15]));
      ll0 += a + b;
      const float c = ((st1[0] + st1[1]) + (st1[2] + st1[3])) +
                      ((st1[4] + st1[5]) + (st1[6] + st1[7]));
      const float d = ((st1[8] + st1[9]) + (st1[10] + st1[11])) +
                      ((st1[12] + st1[13]) + (st1[14] + st1[15]));
      ll1 += c + d;
    }

    unsigned a0 = cvt_pk_bf16(st0[0], st0[1]), b0 = cvt_pk_bf16(st0[4], st0[5]);
    unsigned a1 = cvt_pk_bf16(st0[2], st0[3]), b1 = cvt_pk_bf16(st0[6], st0[7]);
    unsigned a2 = cvt_pk_bf16(st0[8], st0[9]), b2 = cvt_pk_bf16(st0[12], st0[13]);
    unsigned a3 = cvt_pk_bf16(st0[10], st0[11]), b3 = cvt_pk_bf16(st0[14], st0[15]);
    unsigned c0 = cvt_pk_bf16(st1[0], st1[1]), d0 = cvt_pk_bf16(st1[4], st1[5]);
    unsigned c1 = cvt_pk_bf16(st1[2], st1[3]), d1 = cvt_pk_bf16(st1[6], st1[7]);
    unsigned c2 = cvt_pk_bf16(st1[8], st1[9]), d2 = cvt_pk_bf16(st1[12], st1[13]);
    unsigned c3 = cvt_pk_bf16(st1[10], st1[11]), d3 = cvt_pk_bf16(st1[14], st1[15]);
    swap32(a0, b0);
    swap32(a1, b1);
    swap32(a2, b2);
    swap32(a3, b3);
    swap32(c0, d0);
    swap32(c1, d1);
    swap32(c2, d2);
    swap32(c3, d3);
    const u32x4 pwA0 = {a0, a1, b0, b1};
    const u32x4 pwA1 = {a2, a3, b2, b3};
    const u32x4 pwB0 = {c0, c1, d0, d1};
    const u32x4 pwB1 = {c2, c3, d2, d3};
    const bf16x8 pa0 = __builtin_bit_cast(bf16x8, pwA0);
    const bf16x8 pa1 = __builtin_bit_cast(bf16x8, pwA1);
    const bf16x8 pb0 = __builtin_bit_cast(bf16x8, pwB0);
    const bf16x8 pb1 = __builtin_bit_cast(bf16x8, pwB1);

    __builtin_amdgcn_s_setprio(1);
    o00 = MFMA32(pa0, v00, o00);
    o10 = MFMA32(pb0, v00, o10);
    o01 = MFMA32(pa0, v10, o01);
    o11 = MFMA32(pb0, v10, o11);
    o00 = MFMA32(pa1, v01, o00);
    o10 = MFMA32(pb1, v01, o10);
    o01 = MFMA32(pa1, v11, o01);
    o11 = MFMA32(pb1, v11, o11);
    __builtin_amdgcn_s_setprio(0);
  }
#undef STAGE

  float* me = (float*)&KV[s][0];  // 4096 floats
#pragma unroll
  for (int rr = 0; rr < 16; ++rr) {
    const int crow = (rr & 3) + 8 * (rr >> 2) + 4 * h5;
    me[crow * 64 + lq] = o00[rr];
    me[crow * 64 + 32 + lq] = o01[rr];
    me[(32 + crow) * 64 + lq] = o10[rr];
    me[(32 + crow) * 64 + 32 + lq] = o11[rr];
  }
  ll0 += __shfl_xor(ll0, 32);
  ll1 += __shfl_xor(ll1, 32);
  if (h5 == 0) {
    mls[s][0][lq] = ll0;
    mls[s][1][lq] = ll1;
  }
  __syncthreads();

  const float* om = (const float*)&KV[0][0];  // wave stride 4096 floats
  const int b = bh >> 4, h = bh & (NHEAD - 1);
  const int r2 = tidx >> 2;        // q-row 0..63
  const int d0 = (tidx & 3) * 16;  // d group (16 elems)
  const float lsum = mls[0][r2 >> 5][r2 & 31] + mls[1][r2 >> 5][r2 & 31] +
                     mls[2][r2 >> 5][r2 & 31] + mls[3][r2 >> 5][r2 & 31];
  const float inv = __builtin_amdgcn_rcpf(lsum);
  const size_t base = (size_t)(b * S_LEN + qbase + r2) * DMODEL + h * HDIM + d0;
#pragma unroll
  for (int i = 0; i < 16; ++i) {
    const int o = r2 * 64 + d0 + i;
    const float v = om[o] + om[4096 + o] + om[8192 + o] + om[12288 + o];
    ctx[base + i] = f2bf(v * inv);
  }
}

extern "C" void kernel_launch(void* const* d_in, const int* in_sizes, int n_in,
                              void* d_out, int out_size, void* d_ws, size_t ws_size,
                              hipStream_t stream) {
  const float* x = (const float*)d_in[0];
  const float* Wq = (const float*)d_in[1];
  const float* Wk = (const float*)d_in[2];
  const float* Wv = (const float*)d_in[3];
  const float* Wo = (const float*)d_in[4];
  const float* bo = (const float*)d_in[5];

  const size_t XN = (size_t)MROWS * DMODEL;   // 4096*1024
  const size_t WN = (size_t)DMODEL * DMODEL;  // 1024*1024

  short* ws = (short*)d_ws;
  short* xb = ws;
  short* Wqb = xb + XN;  // Wq,Wk,Wv,Wo contiguous ([3072+1024][1024])
  short* Wob = Wqb + 3 * WN;
  short* Qb = Wob + WN;  // Q,K,V contiguous
  short* Kb = Qb + XN;
  short* Vb = Kb + XN;
  short* ctxb = Vb + XN;
  if (ws_size < (5 * XN + 4 * WN) * sizeof(short)) return;

  cvt_all<<<2048, 256, 0, stream>>>(x, Wq, Wk, Wv, Wo, xb);

  gemm_qkv8<<<dim3(MROWS / 256, 3 * DMODEL / 256), 512, 0, stream>>>(xb, Wqb, Qb);

  attn_kernel<<<1024, 256, 0, stream>>>(Qb, Kb, Vb, ctxb);

  gemm_out<<<dim3(MROWS / 64, DMODEL / 64), 256, 0, stream>>>(ctxb, Wob, (float*)d_out,
                                                              bo);
}